// Round 1
// baseline (453.419 us; speedup 1.0000x reference)
//
#include <hip/hip_runtime.h>

#define AS1 __attribute__((address_space(1)))
#define AS3 __attribute__((address_space(3)))

typedef __attribute__((ext_vector_type(8))) short bf16x8;
typedef __attribute__((ext_vector_type(4))) float f32x4;

__device__ __forceinline__ unsigned short f2bf(float f) {
    unsigned int u = __float_as_uint(f);
    u += 0x7fffu + ((u >> 16) & 1u);   // RNE
    return (unsigned short)(u >> 16);
}
__device__ __forceinline__ float bf2f(unsigned short h) {
    return __uint_as_float(((unsigned int)h) << 16);
}

__device__ __forceinline__ void gload16(const void* g, void* l) {
    __builtin_amdgcn_global_load_lds((const AS1 unsigned int*)g, (AS3 unsigned int*)l, 16, 0, 0);
}

#define MFMA(a, b, c) __builtin_amdgcn_mfma_f32_16x16x32_bf16(a, b, c, 0, 0, 0)

// ---------------------------------------------------------------- converts
__global__ void cvt_f32_bf16(const float* __restrict__ src, unsigned short* __restrict__ dst, int n4) {
    const int i = blockIdx.x * blockDim.x + threadIdx.x;
    if (i >= n4) return;
    const float4 v = reinterpret_cast<const float4*>(src)[i];
    ushort4 o;
    o.x = f2bf(v.x); o.y = f2bf(v.y); o.z = f2bf(v.z); o.w = f2bf(v.w);
    reinterpret_cast<ushort4*>(dst)[i] = o;
}

// ------------------------------------------------------------- RoPE tables
// combined dual-RoPE angle: (t + floor((t/576)*0.5)) * theta_j, theta_j = 10000^(-j/32)
__global__ void rope_table(float* __restrict__ cosT, float* __restrict__ sinT) {
    const int i = blockIdx.x * 256 + threadIdx.x;  // 2048*32
    const int t = i >> 5, j = i & 31;
    const int fid = t / 576;
    const float p = (float)(t + (fid >> 1));
    const float theta = powf(10000.0f, -(float)j / 32.0f);
    const float ang = p * theta;
    cosT[i] = cosf(ang);
    sinT[i] = sinf(ang);
}

// in-place RoPE on [B*H*T][64] bf16
__global__ void rope_apply(unsigned short* __restrict__ buf,
                           const float* __restrict__ cosT, const float* __restrict__ sinT) {
    const int i = blockIdx.x * 256 + threadIdx.x;  // B*H*T*32 = 4194304
    const int row = i >> 5;
    const int j = i & 31;
    const int t = row & 2047;
    const float c = cosT[t * 32 + j];
    const float s = sinT[t * 32 + j];
    unsigned short* p = buf + (size_t)row * 64;
    const float x1 = bf2f(p[j]);
    const float x2 = bf2f(p[j + 32]);
    p[j]      = f2bf(x1 * c - x2 * s);
    p[j + 32] = f2bf(x2 * c + x1 * s);
}

// ------------------------------------------------------------------- GEMM
// C[M,N] = A[M,K] * W[N,K]^T + bias.  M=4096, N=2048, K=2048.
// MODE 0: z in {0,1,2} picks (W,bias,out); out bf16 written transposed to [B,H,T,64].
// MODE 1: out fp32 [M,N] = d_out.
template <int MODE>
__global__ __launch_bounds__(256, 2)
void gemm128(const unsigned short* __restrict__ A,
             const unsigned short* __restrict__ W,
             const float* __restrict__ b0, const float* __restrict__ b1, const float* __restrict__ b2,
             unsigned short* __restrict__ O0, unsigned short* __restrict__ O1, unsigned short* __restrict__ O2,
             float* __restrict__ Of) {
    constexpr int K = 2048, LDA = 2048;
    const int tid = threadIdx.x;
    const int lane = tid & 63;
    const int w = tid >> 6;
    const int wr = w >> 1, wc = w & 1;
    const int brow = blockIdx.y * 128;
    const int bcol = blockIdx.x * 128;
    const int z = blockIdx.z;
    const unsigned short* Bmat = W + (size_t)z * 4194304;
    const float* bias = (MODE == 1) ? b0 : (z == 0 ? b0 : (z == 1 ? b1 : b2));

    __shared__ unsigned char lds[32768];
    unsigned char* Asm_ = lds;           // [128][64] bf16, XOR-swizzled 16B blocks
    unsigned char* Bsm  = lds + 16384;

    f32x4 acc[4][4] = {};
    const int l15 = lane & 15;
    const int lg = lane >> 4;

    for (int kt = 0; kt < K / 64; ++kt) {
        const int k0g = kt * 64;
        __syncthreads();
#pragma unroll
        for (int s = 0; s < 4; ++s) {
            const int c = w * 256 + s * 64 + lane;   // chunk id 0..1023
            const int row = c >> 3;
            const int cb = (c & 7) ^ (row & 7);      // pre-swizzled global source (rule 21)
            gload16(A    + (size_t)(brow + row) * LDA + k0g + cb * 8, Asm_ + (w * 256 + s * 64) * 16);
            gload16(Bmat + (size_t)(bcol + row) * LDA + k0g + cb * 8, Bsm  + (w * 256 + s * 64) * 16);
        }
        asm volatile("s_waitcnt vmcnt(0)" ::: "memory");
        __syncthreads();

#pragma unroll
        for (int kk = 0; kk < 2; ++kk) {
            bf16x8 af[4], bfr[4];
            const int koff = kk * 64 + lg * 16;  // byte offset within 128B row
#pragma unroll
            for (int m = 0; m < 4; ++m) {
                const int row = wr * 64 + m * 16 + l15;
                af[m] = *(const bf16x8*)(Asm_ + row * 128 + (koff ^ ((row & 7) << 4)));
            }
#pragma unroll
            for (int n = 0; n < 4; ++n) {
                const int row = wc * 64 + n * 16 + l15;
                bfr[n] = *(const bf16x8*)(Bsm + row * 128 + (koff ^ ((row & 7) << 4)));
            }
#pragma unroll
            for (int m = 0; m < 4; ++m)
#pragma unroll
                for (int n = 0; n < 4; ++n)
                    acc[m][n] = MFMA(af[m], bfr[n], acc[m][n]);
        }
    }

#pragma unroll
    for (int m = 0; m < 4; ++m) {
#pragma unroll
        for (int n = 0; n < 4; ++n) {
            const int cg = bcol + wc * 64 + n * 16 + l15;
            const float bv_ = bias[cg];
#pragma unroll
            for (int r = 0; r < 4; ++r) {
                const int rg = brow + wr * 64 + m * 16 + lg * 4 + r;
                const float v = acc[m][n][r] + bv_;
                if (MODE == 0) {
                    unsigned short* Ot = (z == 0 ? O0 : (z == 1 ? O1 : O2));
                    const int bb = rg >> 11, t = rg & 2047, hh = cg >> 6, d = cg & 63;
                    Ot[(((size_t)bb * 32 + hh) * 2048 + t) * 64 + d] = f2bf(v);
                } else {
                    Of[(size_t)rg * 2048 + cg] = v;
                }
            }
        }
    }
}

// -------------------------------------------------------- flash attention
// grid (32 qtiles, 64 bh), 256 threads (4 waves, 16 q-rows each), causal.
__global__ __launch_bounds__(256, 2)
void attn(const unsigned short* __restrict__ Qg, const unsigned short* __restrict__ Kg,
          const unsigned short* __restrict__ Vg, unsigned short* __restrict__ Og) {
    const int qt = blockIdx.x;
    const int bh = blockIdx.y;
    const int b = bh >> 5, h = bh & 31;
    const int tid = threadIdx.x;
    const int lane = tid & 63;
    const int w = tid >> 6;
    const int l15 = lane & 15, lg = lane >> 4;

    const unsigned short* Q = Qg + (size_t)bh * (2048 * 64);
    const unsigned short* K = Kg + (size_t)bh * (2048 * 64);
    const unsigned short* V = Vg + (size_t)bh * (2048 * 64);

    __shared__ unsigned char Ks[8192];     // [64 k][64 d] bf16, swizzled
    __shared__ unsigned char Vs[8192];     // transposed [64 d][64 k] bf16, swizzled
    __shared__ unsigned char Ps[4][2048];  // per-wave P [16 q][64 k] bf16, swizzled

    const int qbase = qt * 64 + w * 16;

    bf16x8 qf[2];
#pragma unroll
    for (int h2 = 0; h2 < 2; ++h2)
        qf[h2] = *(const bf16x8*)(Q + (size_t)(qbase + l15) * 64 + h2 * 32 + lg * 8);

    f32x4 oacc[4] = {};
    float mrow[4] = {-1e30f, -1e30f, -1e30f, -1e30f};
    float lrow[4] = {0.f, 0.f, 0.f, 0.f};

    for (int kt = 0; kt <= qt; ++kt) {
        __syncthreads();
        // stage K tile (reg-staged, both-sides XOR swizzle)
#pragma unroll
        for (int s = 0; s < 2; ++s) {
            const int c = s * 256 + tid;  // 0..511
            const int row = c >> 3;
            const int cb = c & 7;
            const uint4 kv = *(const uint4*)(K + (size_t)(kt * 64 + row) * 64 + cb * 8);
            *(uint4*)(Ks + row * 128 + ((cb * 16) ^ ((row & 7) << 4))) = kv;
        }
        // stage V transposed: wave w covers k-rows = i*4+w; lane = d
#pragma unroll
        for (int i = 0; i < 16; ++i) {
            const int krow = i * 4 + w;
            const unsigned short vv = V[(size_t)(kt * 64 + krow) * 64 + lane];
            *(unsigned short*)(Vs + lane * 128 + ((krow * 2) ^ ((lane & 7) << 4))) = vv;
        }
        __syncthreads();

        // S = Q K^T  (D: row=q=(lg*4+r), col=k=l15)
        f32x4 sac[4] = {};
#pragma unroll
        for (int nt = 0; nt < 4; ++nt) {
#pragma unroll
            for (int h2 = 0; h2 < 2; ++h2) {
                const int kcol = nt * 16 + l15;
                const int koff = h2 * 64 + lg * 16;
                const bf16x8 kf = *(const bf16x8*)(Ks + kcol * 128 + (koff ^ ((kcol & 7) << 4)));
                sac[nt] = MFMA(qf[h2], kf, sac[nt]);
            }
        }

        const bool diag = (kt == qt);
        float pmax[4] = {-1e30f, -1e30f, -1e30f, -1e30f};
#pragma unroll
        for (int nt = 0; nt < 4; ++nt) {
#pragma unroll
            for (int r = 0; r < 4; ++r) {
                float sv = sac[nt][r] * 0.125f;
                if (diag && (nt * 16 + l15 > w * 16 + lg * 4 + r)) sv = -1e30f;
                sac[nt][r] = sv;
                pmax[r] = fmaxf(pmax[r], sv);
            }
        }
#pragma unroll
        for (int mk = 1; mk < 16; mk <<= 1)
#pragma unroll
            for (int r = 0; r < 4; ++r)
                pmax[r] = fmaxf(pmax[r], __shfl_xor(pmax[r], mk));

        float psum[4];
#pragma unroll
        for (int r = 0; r < 4; ++r) {
            const float mnew = fmaxf(mrow[r], pmax[r]);
            const float sc = __expf(mrow[r] - mnew);
            mrow[r] = mnew;
            lrow[r] *= sc;
            psum[r] = 0.f;
#pragma unroll
            for (int dt = 0; dt < 4; ++dt) oacc[dt][r] *= sc;
        }
#pragma unroll
        for (int nt = 0; nt < 4; ++nt) {
#pragma unroll
            for (int r = 0; r < 4; ++r) {
                const float p = __expf(sac[nt][r] - mrow[r]);
                psum[r] += p;
                const int qrow = lg * 4 + r;
                const int kcol = nt * 16 + l15;
                *(unsigned short*)(Ps[w] + qrow * 128 + ((kcol * 2) ^ ((qrow & 7) << 4))) = f2bf(p);
            }
        }
#pragma unroll
        for (int mk = 1; mk < 16; mk <<= 1)
#pragma unroll
            for (int r = 0; r < 4; ++r)
                psum[r] += __shfl_xor(psum[r], mk);
#pragma unroll
        for (int r = 0; r < 4; ++r) lrow[r] += psum[r];

        asm volatile("s_waitcnt lgkmcnt(0)" ::: "memory");
        __builtin_amdgcn_sched_barrier(0);

        // O += P V   (per-wave Ps, shared Vs)
#pragma unroll
        for (int h2 = 0; h2 < 2; ++h2) {
            const int koff = h2 * 64 + lg * 16;
            const bf16x8 pf = *(const bf16x8*)(Ps[w] + l15 * 128 + (koff ^ ((l15 & 7) << 4)));
#pragma unroll
            for (int dt = 0; dt < 4; ++dt) {
                const int dcol = dt * 16 + l15;
                const bf16x8 vf = *(const bf16x8*)(Vs + dcol * 128 + (koff ^ ((dcol & 7) << 4)));
                oacc[dt] = MFMA(pf, vf, oacc[dt]);
            }
        }
    }

    // epilogue: O/l written to [B*T][2048] bf16
#pragma unroll
    for (int dt = 0; dt < 4; ++dt) {
#pragma unroll
        for (int r = 0; r < 4; ++r) {
            const int t = qbase + lg * 4 + r;
            const float v = oacc[dt][r] / lrow[r];
            Og[(size_t)(b * 2048 + t) * 2048 + h * 64 + dt * 16 + l15] = f2bf(v);
        }
    }
}

// ------------------------------------------------------------------ launch
extern "C" void kernel_launch(void* const* d_in, const int* in_sizes, int n_in,
                              void* d_out, int out_size, void* d_ws, size_t ws_size,
                              hipStream_t stream) {
    const float* hs = (const float*)d_in[0];
    const float* Wq = (const float*)d_in[1];
    const float* bq = (const float*)d_in[2];
    const float* Wk = (const float*)d_in[3];
    const float* bk = (const float*)d_in[4];
    const float* Wv = (const float*)d_in[5];
    const float* bv = (const float*)d_in[6];
    const float* Wo = (const float*)d_in[7];
    const float* bo = (const float*)d_in[8];
    float* out = (float*)d_out;

    char* ws = (char*)d_ws;
    unsigned short* Xb = (unsigned short*)ws;                  // 16 MB  [4096][2048] bf16
    unsigned short* Wb = (unsigned short*)(ws + (16u << 20));  // 32 MB  [4][2048][2048] bf16
    unsigned short* Qb = (unsigned short*)(ws + (48u << 20));  // 16 MB  [B,H,T,64]
    unsigned short* Kb = (unsigned short*)(ws + (64u << 20));  // 16 MB
    unsigned short* Vb = (unsigned short*)(ws + (80u << 20));  // 16 MB
    unsigned short* Ob = Xb;                                   // alias: X dead after QKV GEMM
    float* cosT = (float*)(ws + (96u << 20));                  // 256 KB
    float* sinT = cosT + 65536;                                // 256 KB

    cvt_f32_bf16<<<8192, 256, 0, stream>>>(hs, Xb, 2097152);
    cvt_f32_bf16<<<4096, 256, 0, stream>>>(Wq, Wb + (size_t)0 * 4194304, 1048576);
    cvt_f32_bf16<<<4096, 256, 0, stream>>>(Wk, Wb + (size_t)1 * 4194304, 1048576);
    cvt_f32_bf16<<<4096, 256, 0, stream>>>(Wv, Wb + (size_t)2 * 4194304, 1048576);
    cvt_f32_bf16<<<4096, 256, 0, stream>>>(Wo, Wb + (size_t)3 * 4194304, 1048576);
    rope_table<<<256, 256, 0, stream>>>(cosT, sinT);

    gemm128<0><<<dim3(16, 32, 3), 256, 0, stream>>>(Xb, Wb, bq, bk, bv, Qb, Kb, Vb, nullptr);

    rope_apply<<<16384, 256, 0, stream>>>(Qb, cosT, sinT);
    rope_apply<<<16384, 256, 0, stream>>>(Kb, cosT, sinT);

    attn<<<dim3(32, 64), 256, 0, stream>>>(Qb, Kb, Vb, Ob);

    gemm128<1><<<dim3(16, 32, 1), 256, 0, stream>>>(Ob, Wb + (size_t)3 * 4194304, bo, bo, bo,
                                                    nullptr, nullptr, nullptr, out);
}